// Round 2
// baseline (774.349 us; speedup 1.0000x reference)
//
#include <hip/hip_runtime.h>
#include <hip/hip_bf16.h>

// CfC / liquid-RNN scan. B=4, C=16, T=32, H=64, W=64, UNITS=32, BACKBONE=64.
// Reference dtype is float32; harness MAY have converted to bf16 — we detect
// at runtime (deterministic, data-driven, graph-capture safe) and dispatch a
// templated path. Weights are read via wave-uniform scalar loads (s_load ->
// SGPR FMA operand); only activations round-trip through LDS.

#define CIN      16
#define UNITS    32
#define BACKBONE 64
#define CZ       48      // CIN + UNITS
#define TSTEPS   32
#define HW       4096    // 64*64
#define NPIX     64      // pixels per block
#define NTHREADS 512     // 8 waves
#define NWAVES   8

typedef __hip_bfloat16 bf16;

__device__ __forceinline__ float ldE(const float* p, int i) { return p[i]; }
__device__ __forceinline__ float ldE(const bf16*  p, int i) { return __bfloat162float(p[i]); }
__device__ __forceinline__ void  stE(float* p, int i, float v) { p[i] = v; }
__device__ __forceinline__ void  stE(bf16*  p, int i, float v) { p[i] = __float2bfloat16(v); }

__device__ __forceinline__ float tanh_fast(float x) {
    // tanh(x) = 1 - 2/(exp(2x)+1); saturates correctly as exp -> 0 / inf
    float e = __expf(2.0f * x);
    return 1.0f - __fdividef(2.0f, e + 1.0f);
}
__device__ __forceinline__ float sigmoid_fast(float x) {
    return __fdividef(1.0f, 1.0f + __expf(-x));
}

template <typename T>
__device__ __forceinline__ void run_scan(
    const T* __restrict__ x,   const T* __restrict__ Wb,   const T* __restrict__ bb,
    const T* __restrict__ Wff1, const T* __restrict__ bff1,
    const T* __restrict__ Wff2, const T* __restrict__ bff2,
    const T* __restrict__ Wta,  const T* __restrict__ bta,
    const T* __restrict__ Wtb,  const T* __restrict__ btb,
    T* __restrict__ out,
    float (*zs)[NPIX], float (*as_)[NPIX])
{
    const int tid = threadIdx.x;
    const int pix = tid & 63;
    const int grp = __builtin_amdgcn_readfirstlane(tid >> 6);  // wave id 0..7 (SGPR)

    const int gpix = blockIdx.x * NPIX;   // global pixel id
    const int b    = gpix >> 12;          // / 4096
    const int pinb = gpix & 4095;

    const int kbase = grp * (BACKBONE / NWAVES);  // 8 backbone rows per wave
    const int ubase = grp * (UNITS / NWAVES);     // 4 units (x 4 heads) per wave

    // biases: wave-uniform -> scalar loads, live in SGPRs
    float bbr[8];
    #pragma unroll
    for (int k = 0; k < 8; ++k) bbr[k] = ldE(bb, kbase + k);
    float bh0[4], bh1[4], bh2[4], bh3[4];
    #pragma unroll
    for (int j = 0; j < 4; ++j) {
        bh0[j] = ldE(bff1, ubase + j);
        bh1[j] = ldE(bff2, ubase + j);
        bh2[j] = ldE(bta,  ubase + j);
        bh3[j] = ldE(btb,  ubase + j);
    }

    // h0 = 0 (zs rows CIN..CIN+UNITS-1)
    for (int i = tid; i < UNITS * NPIX; i += NTHREADS)
        zs[CIN + (i >> 6)][i & 63] = 0.0f;

    for (int t = 0; t < TSTEPS; ++t) {
        // ---- stage x_t into zs rows 0..15 (coalesced global, stride-1 LDS) ----
        #pragma unroll
        for (int i = 0; i < (CIN * NPIX) / NTHREADS; ++i) {   // 2 iters
            int e = tid + i * NTHREADS;
            int c = e >> 6, p = e & 63;
            zs[c][p] = ldE(x, ((b * CIN + c) * TSTEPS + t) * HW + pinb + p);
        }
        __syncthreads();

        // ---- backbone: wave grp computes rows kbase..kbase+7 for pixel=lane ----
        {
            float acc[8];
            #pragma unroll
            for (int k = 0; k < 8; ++k) acc[k] = bbr[k];
            #pragma unroll 4
            for (int c = 0; c < CZ; ++c) {
                float zc = zs[c][pix];
                #pragma unroll
                for (int k = 0; k < 8; ++k)
                    acc[k] = __fmaf_rn(ldE(Wb, (kbase + k) * CZ + c), zc, acc[k]);
            }
            #pragma unroll
            for (int k = 0; k < 8; ++k)
                as_[kbase + k][pix] = 1.7159f * tanh_fast(0.666f * acc[k]);
        }
        __syncthreads();

        // ---- heads: wave grp computes units ubase..ubase+3 for all 4 heads,
        //      gate epilogue fused in-register ----
        {
            float a0[4], a1[4], a2[4], a3[4];
            #pragma unroll
            for (int j = 0; j < 4; ++j) { a0[j]=bh0[j]; a1[j]=bh1[j]; a2[j]=bh2[j]; a3[j]=bh3[j]; }
            #pragma unroll 4
            for (int c = 0; c < BACKBONE; ++c) {
                float ac = as_[c][pix];
                #pragma unroll
                for (int j = 0; j < 4; ++j) {
                    int wi = (ubase + j) * BACKBONE + c;
                    a0[j] = __fmaf_rn(ldE(Wff1, wi), ac, a0[j]);
                    a1[j] = __fmaf_rn(ldE(Wff2, wi), ac, a1[j]);
                    a2[j] = __fmaf_rn(ldE(Wta,  wi), ac, a2[j]);
                    a3[j] = __fmaf_rn(ldE(Wtb,  wi), ac, a3[j]);
                }
            }
            #pragma unroll
            for (int j = 0; j < 4; ++j) {
                float f1 = tanh_fast(a0[j]);
                float f2 = tanh_fast(a1[j]);
                float ti = sigmoid_fast(a2[j] + a3[j]);
                float hn = f1 + ti * (f2 - f1);
                int u = ubase + j;
                zs[CIN + u][pix] = hn;                                 // h feedback
                stE(out, ((b * UNITS + u) * TSTEPS + t) * HW + pinb + pix, hn);
            }
        }
        __syncthreads();   // protect zs (h) and as_ before next iteration
    }
}

__global__ __launch_bounds__(NTHREADS, 1)
void cfc_kernel(const void* x, const void* Wb, const void* bb,
                const void* Wff1, const void* bff1,
                const void* Wff2, const void* bff2,
                const void* Wta,  const void* bta,
                const void* Wtb,  const void* btb,
                void* out)
{
    __shared__ float zs[CZ][NPIX];        // rows 0..15: x_t, 16..47: h
    __shared__ float as_[BACKBONE][NPIX]; // backbone activations

    // ---- dtype probe: reinterpret first 64 ushorts of x as bf16. If the
    // buffer actually holds fp32, the odd halves are mantissa bits -> random
    // exponents -> huge/NaN values. Deterministic, same result every call. ----
    const unsigned short* xu = (const unsigned short*)x;
    int isf32 = 0;
    #pragma unroll 1
    for (int i = 0; i < 64; ++i) {
        float v = __uint_as_float(((unsigned)xu[i]) << 16);
        float a = __builtin_fabsf(v);
        if (!(a <= 1024.0f)) isf32 = 1;   // catches huge values and NaN
    }

    if (isf32) {
        run_scan<float>((const float*)x, (const float*)Wb, (const float*)bb,
                        (const float*)Wff1, (const float*)bff1,
                        (const float*)Wff2, (const float*)bff2,
                        (const float*)Wta,  (const float*)bta,
                        (const float*)Wtb,  (const float*)btb,
                        (float*)out, zs, as_);
    } else {
        run_scan<bf16>((const bf16*)x, (const bf16*)Wb, (const bf16*)bb,
                       (const bf16*)Wff1, (const bf16*)bff1,
                       (const bf16*)Wff2, (const bf16*)bff2,
                       (const bf16*)Wta,  (const bf16*)bta,
                       (const bf16*)Wtb,  (const bf16*)btb,
                       (bf16*)out, zs, as_);
    }
}

extern "C" void kernel_launch(void* const* d_in, const int* in_sizes, int n_in,
                              void* d_out, int out_size, void* d_ws, size_t ws_size,
                              hipStream_t stream) {
    dim3 grid(4 * HW / NPIX);   // 256 blocks, one 64-pixel slab each
    cfc_kernel<<<grid, NTHREADS, 0, stream>>>(
        d_in[0], d_in[1], d_in[2], d_in[3], d_in[4], d_in[5],
        d_in[6], d_in[7], d_in[8], d_in[9], d_in[10], d_out);
}

// Round 3
// 189.355 us; speedup vs baseline: 4.0894x; 4.0894x over previous
//
#include <hip/hip_runtime.h>
#include <hip/hip_bf16.h>

// CfC / liquid-RNN scan on MFMA. B=4, C=16, T=32, H=64, W=64, U=32, BB=64.
// Buffers are fp32 (proven R2: WRITE_SIZE == out_size*4B).
// Per step: backbone D[64xNpix] = Wb(64x48)*Z(48xNpix); heads D[4x32xNpix] =
// Wh(32x64)*A(64xNpix). fp32 emulated via bf16 hi/lo split: 3 MFMAs
// (hi*hi + hi*lo + lo*hi), error ~2^-17 — well under the 2e-2 threshold.
// Weights live in VGPRs as A-fragments, loaded ONCE before the t-loop
// (R2 showed per-step weight loads cost 3.5x the FMA floor).
//
// LDS activation layout: K-contiguous per pixel (zT[p][c], aT[p][k]) so
// A/B fragments are single ds_read_b128 (8 consecutive k per lane:
// A[m=lane&15][k=quad*8+j], B[k=quad*8+j][n=lane&15]).  16B chunks are
// XOR-swizzled by (pixel&7) to keep fragment reads ~2-way bank aliasing.

#define CIN      16
#define UNITS    32
#define BACKBONE 64
#define CZ       48
#define TSTEPS   32
#define HW       4096
#define NPIX     32       // pixels per block
#define NTHREADS 256      // 4 waves
#define KPAD     64       // zT K dim padded 48->64 (pad stays zero)

typedef __attribute__((ext_vector_type(8))) short  short8;
typedef __attribute__((ext_vector_type(4))) short  short4v;
typedef __attribute__((ext_vector_type(8))) __bf16 bf16x8;
typedef __attribute__((ext_vector_type(4))) float  float4v;

__device__ __forceinline__ unsigned short bf16_rne(float f) {
    unsigned u = __float_as_uint(f);
    return (unsigned short)((u + 0x7FFFu + ((u >> 16) & 1u)) >> 16);
}
__device__ __forceinline__ float bf16_tof(unsigned short h) {
    return __uint_as_float(((unsigned)h) << 16);
}
__device__ __forceinline__ float tanh_fast(float x) {
    float e = __expf(2.0f * x);                 // saturates correctly at +/-inf
    return 1.0f - __fdividef(2.0f, e + 1.0f);
}
__device__ __forceinline__ float sigmoid_fast(float x) {
    return __fdividef(1.0f, 1.0f + __expf(-x));
}
__device__ __forceinline__ float4v mfma16(bf16x8 a, bf16x8 b, float4v c) {
    return __builtin_amdgcn_mfma_f32_16x16x32_bf16(a, b, c, 0, 0, 0);
}
// split 8 fp32 (v[8]) into hi/lo bf16 fragments
__device__ __forceinline__ void split8(const float* v, bf16x8& hi, bf16x8& lo) {
    short8 sh, sl;
    #pragma unroll
    for (int j = 0; j < 8; ++j) {
        unsigned short h = bf16_rne(v[j]);
        sh[j] = (short)h;
        sl[j] = (short)bf16_rne(v[j] - bf16_tof(h));
    }
    hi = __builtin_bit_cast(bf16x8, sh);
    lo = __builtin_bit_cast(bf16x8, sl);
}

__global__ __launch_bounds__(NTHREADS, 2)
void cfc_mfma_kernel(const float* __restrict__ x,   const float* __restrict__ Wb,
                     const float* __restrict__ bb,
                     const float* __restrict__ Wff1, const float* __restrict__ bff1,
                     const float* __restrict__ Wff2, const float* __restrict__ bff2,
                     const float* __restrict__ Wta,  const float* __restrict__ bta,
                     const float* __restrict__ Wtb,  const float* __restrict__ btb,
                     float* __restrict__ out)
{
    // bf16 activation buffers, hi/lo pair each.  [pixel][KPAD] with 16B-chunk
    // xor-swizzle: element (p,c) lives at p*64 + ((c>>3)^(p&7))*8 + (c&7).
    __shared__ unsigned short zhi[NPIX * KPAD], zlo[NPIX * KPAD];
    __shared__ unsigned short ahi[NPIX * KPAD], alo[NPIX * KPAD];

    const int tid  = threadIdx.x;
    const int wave = tid >> 6;
    const int lane = tid & 63;
    const int ln   = lane & 15;     // MFMA m/n index
    const int lq   = lane >> 4;     // MFMA quad

    const int gpix = blockIdx.x * NPIX;
    const int b    = gpix >> 12;
    const int pinb = gpix & 4095;

    // ---------------- weights -> VGPR A-fragments (once) ----------------
    const int mt = wave;            // backbone M-tile (rows 16*mt..16*mt+15)
    bf16x8 Abb_hi[2], Abb_lo[2];
    #pragma unroll
    for (int kt = 0; kt < 2; ++kt) {
        const int m  = mt * 16 + ln;
        const int k0 = kt * 32 + lq * 8;
        float v[8];
        #pragma unroll
        for (int j = 0; j < 8; ++j) {
            int k  = k0 + j;
            int ki = (k < CZ) ? k : (CZ - 1);           // stay in-bounds
            float raw = Wb[m * CZ + ki];
            v[j] = (k < CZ) ? raw : 0.0f;               // zero-pad K 48..63
        }
        split8(v, Abb_hi[kt], Abb_lo[kt]);
    }

    const int pm = wave & 1;        // head unit-tile (units 16*pm..)
    const int pn = wave >> 1;       // head pixel-tile (pixels 16*pn..)
    const float* Wh[4] = {Wff1, Wff2, Wta, Wtb};
    bf16x8 Ah_hi[4][2], Ah_lo[4][2];
    #pragma unroll
    for (int h = 0; h < 4; ++h) {
        #pragma unroll
        for (int kt = 0; kt < 2; ++kt) {
            const int u  = pm * 16 + ln;
            const int k0 = kt * 32 + lq * 8;
            float v[8];
            #pragma unroll
            for (int j = 0; j < 8; ++j) v[j] = Wh[h][u * BACKBONE + k0 + j];
            split8(v, Ah_hi[h][kt], Ah_lo[h][kt]);
        }
    }

    // biases, mapped to the C/D layout (row = lq*4 + r)
    float bbias[4];
    #pragma unroll
    for (int r = 0; r < 4; ++r) bbias[r] = bb[mt * 16 + lq * 4 + r];
    const float* Bh[4] = {bff1, bff2, bta, btb};
    float hbias[4][4];
    #pragma unroll
    for (int h = 0; h < 4; ++h)
        #pragma unroll
        for (int r = 0; r < 4; ++r) hbias[h][r] = Bh[h][pm * 16 + lq * 4 + r];

    // ---------------- zero zT (h0 = 0, and K-pad 48..63 stays 0) --------
    for (int i = tid; i < NPIX * KPAD / 2; i += NTHREADS) {
        ((unsigned*)zhi)[i] = 0u;
        ((unsigned*)zlo)[i] = 0u;
    }

    // x staging assignment: thread -> (pixel, channel pair)
    const int xc0 = (tid >> 5) * 2;     // 0,2,...,14
    const int xp  = tid & 31;
    const float* xbase = x + (size_t)(b * CIN) * (TSTEPS * HW) + pinb + xp;

    #pragma unroll 1
    for (int t = 0; t < TSTEPS; ++t) {
        // ---- phase 0: stage x_t into zT (k = 0..15) ----
        {
            float v0 = xbase[(xc0    ) * (TSTEPS * HW) + t * HW];
            float v1 = xbase[(xc0 + 1) * (TSTEPS * HW) + t * HW];
            unsigned short h0 = bf16_rne(v0);
            unsigned short h1 = bf16_rne(v1);
            unsigned short l0 = bf16_rne(v0 - bf16_tof(h0));
            unsigned short l1 = bf16_rne(v1 - bf16_tof(h1));
            int off = xp * KPAD + (((xc0 >> 3) ^ (xp & 7)) << 3) + (xc0 & 7);
            *(unsigned*)&zhi[off] = (unsigned)h0 | ((unsigned)h1 << 16);
            *(unsigned*)&zlo[off] = (unsigned)l0 | ((unsigned)l1 << 16);
        }
        __syncthreads();

        // ---- phase 1: backbone MFMA + lecun_tanh -> aT ----
        float4v accb[2];
        #pragma unroll
        for (int nt = 0; nt < 2; ++nt) {
            const int n = nt * 16 + ln;
            float4v acc = {bbias[0], bbias[1], bbias[2], bbias[3]};
            #pragma unroll
            for (int kt = 0; kt < 2; ++kt) {
                int sw  = ((kt << 2) | lq) ^ (n & 7);
                int off = n * KPAD + (sw << 3);
                bf16x8 Bhf = __builtin_bit_cast(bf16x8, *(const short8*)&zhi[off]);
                bf16x8 Blf = __builtin_bit_cast(bf16x8, *(const short8*)&zlo[off]);
                acc = mfma16(Abb_hi[kt], Bhf, acc);
                acc = mfma16(Abb_hi[kt], Blf, acc);
                acc = mfma16(Abb_lo[kt], Bhf, acc);
            }
            accb[nt] = acc;
        }
        #pragma unroll
        for (int nt = 0; nt < 2; ++nt) {
            const int p  = nt * 16 + ln;
            const int k0 = mt * 16 + lq * 4;       // 4 consecutive k, same chunk
            short4v ph, pl;
            #pragma unroll
            for (int r = 0; r < 4; ++r) {
                float g = 1.7159f * tanh_fast(0.666f * accb[nt][r]);
                unsigned short gh = bf16_rne(g);
                ph[r] = (short)gh;
                pl[r] = (short)bf16_rne(g - bf16_tof(gh));
            }
            int sw  = (k0 >> 3) ^ (p & 7);
            int off = p * KPAD + (sw << 3) + (k0 & 7);
            *(short4v*)&ahi[off] = ph;
            *(short4v*)&alo[off] = pl;
        }
        __syncthreads();

        // ---- phase 2: 4 head MFMAs + fused gate epilogue ----
        float4v acch[4];
        {
            const int n = pn * 16 + ln;
            bf16x8 Bhf[2], Blf[2];
            #pragma unroll
            for (int kt = 0; kt < 2; ++kt) {
                int sw  = ((kt << 2) | lq) ^ (n & 7);
                int off = n * KPAD + (sw << 3);
                Bhf[kt] = __builtin_bit_cast(bf16x8, *(const short8*)&ahi[off]);
                Blf[kt] = __builtin_bit_cast(bf16x8, *(const short8*)&alo[off]);
            }
            #pragma unroll
            for (int h = 0; h < 4; ++h) {
                float4v acc = {hbias[h][0], hbias[h][1], hbias[h][2], hbias[h][3]};
                #pragma unroll
                for (int kt = 0; kt < 2; ++kt) {
                    acc = mfma16(Ah_hi[h][kt], Bhf[kt], acc);
                    acc = mfma16(Ah_hi[h][kt], Blf[kt], acc);
                    acc = mfma16(Ah_lo[h][kt], Bhf[kt], acc);
                }
                acch[h] = acc;
            }
        }
        {
            const int pl_ = pn * 16 + ln;
            const int k0  = CIN + pm * 16 + lq * 4;
            short4v hh, hl;
            #pragma unroll
            for (int r = 0; r < 4; ++r) {
                float f1 = tanh_fast(acch[0][r]);
                float f2 = tanh_fast(acch[1][r]);
                float ti = sigmoid_fast(acch[2][r] + acch[3][r]);
                float hn = f1 + ti * (f2 - f1);
                const int u = pm * 16 + lq * 4 + r;
                out[((b * UNITS + u) * TSTEPS + t) * HW + pinb + pl_] = hn;
                unsigned short hb = bf16_rne(hn);
                hh[r] = (short)hb;
                hl[r] = (short)bf16_rne(hn - bf16_tof(hb));
            }
            int sw  = (k0 >> 3) ^ (pl_ & 7);
            int off = pl_ * KPAD + (sw << 3) + (k0 & 7);
            *(short4v*)&zhi[off] = hh;
            *(short4v*)&zlo[off] = hl;
        }
        __syncthreads();   // h/aT hazards vs next iteration
    }
}

extern "C" void kernel_launch(void* const* d_in, const int* in_sizes, int n_in,
                              void* d_out, int out_size, void* d_ws, size_t ws_size,
                              hipStream_t stream) {
    dim3 grid(4 * HW / NPIX);   // 512 blocks -> 2 blocks/CU
    cfc_mfma_kernel<<<grid, NTHREADS, 0, stream>>>(
        (const float*)d_in[0], (const float*)d_in[1], (const float*)d_in[2],
        (const float*)d_in[3], (const float*)d_in[4], (const float*)d_in[5],
        (const float*)d_in[6], (const float*)d_in[7], (const float*)d_in[8],
        (const float*)d_in[9], (const float*)d_in[10],
        (float*)d_out);
}

// Round 5
// 175.148 us; speedup vs baseline: 4.4211x; 1.0811x over previous
//
#include <hip/hip_runtime.h>
#include <hip/hip_bf16.h>

// CfC / liquid-RNN scan on MFMA, R5 = R4 + race fix. fp32 buffers (proven R2).
// R4 post-mortem: missing __syncthreads() between the prologue LDS zero-fill
// and the x_0 staging store -> cross-wave race, nondeterministic replays
// (first launch passed absmax 0.0039, re-validation after graph replay
// failed). R5 adds that single barrier; no other change, so R4's
// occupancy theory (NPIX=16 -> 1024 blocks -> 4 blocks/CU) is tested clean.
// Phase 2 computes ALL 4 heads as one GEMM with row-interleaved weights
// (row = u*4 + h): 16x16 C-tile gives each lane the 4 head values of one
// unit in its 4 acc regs -> in-register gate. 2 barriers/step.
// fp32 via bf16 hi/lo split: hi*hi + hi*lo + lo*hi (3 MFMAs), err ~2^-17.

#define CIN      16
#define UNITS    32
#define BACKBONE 64
#define CZ       48
#define TSTEPS   32
#define HW       4096
#define NPIX     16
#define NTHREADS 256
#define KPAD     64

typedef __attribute__((ext_vector_type(8))) short  short8;
typedef __attribute__((ext_vector_type(4))) short  short4v;
typedef __attribute__((ext_vector_type(8))) __bf16 bf16x8;
typedef __attribute__((ext_vector_type(4))) float  float4v;

__device__ __forceinline__ unsigned short bf16_rne(float f) {
    unsigned u = __float_as_uint(f);
    return (unsigned short)((u + 0x7FFFu + ((u >> 16) & 1u)) >> 16);
}
__device__ __forceinline__ float bf16_tof(unsigned short h) {
    return __uint_as_float(((unsigned)h) << 16);
}
__device__ __forceinline__ float tanh_fast(float x) {
    float e = __expf(2.0f * x);                 // saturates correctly
    return 1.0f - __fdividef(2.0f, e + 1.0f);
}
__device__ __forceinline__ float sigmoid_fast(float x) {
    return __fdividef(1.0f, 1.0f + __expf(-x));
}
__device__ __forceinline__ float4v mfma16(bf16x8 a, bf16x8 b, float4v c) {
    return __builtin_amdgcn_mfma_f32_16x16x32_bf16(a, b, c, 0, 0, 0);
}
__device__ __forceinline__ void split8(const float* v, bf16x8& hi, bf16x8& lo) {
    short8 sh, sl;
    #pragma unroll
    for (int j = 0; j < 8; ++j) {
        unsigned short h = bf16_rne(v[j]);
        sh[j] = (short)h;
        sl[j] = (short)bf16_rne(v[j] - bf16_tof(h));
    }
    hi = __builtin_bit_cast(bf16x8, sh);
    lo = __builtin_bit_cast(bf16x8, sl);
}
// element (pixel p, k) -> ushort offset; 16B chunks xor-swizzled by (p&7)
__device__ __forceinline__ int swoff(int p, int k) {
    return p * KPAD + ((((k >> 3) ^ (p & 7)) << 3) | (k & 7));
}

__global__ __launch_bounds__(NTHREADS, 4)
void cfc_mfma_kernel(const float* __restrict__ x,   const float* __restrict__ Wb,
                     const float* __restrict__ bb,
                     const float* __restrict__ Wff1, const float* __restrict__ bff1,
                     const float* __restrict__ Wff2, const float* __restrict__ bff2,
                     const float* __restrict__ Wta,  const float* __restrict__ bta,
                     const float* __restrict__ Wtb,  const float* __restrict__ btb,
                     float* __restrict__ out)
{
    __shared__ unsigned short zhi[NPIX * KPAD], zlo[NPIX * KPAD];   // z: x|h, K-padded
    __shared__ unsigned short ahi[NPIX * KPAD], alo[NPIX * KPAD];   // backbone act

    const int tid  = threadIdx.x;
    const int wave = tid >> 6;
    const int lane = tid & 63;
    const int ln   = lane & 15;     // MFMA m/n
    const int lq   = lane >> 4;     // MFMA quad

    const int gpix = blockIdx.x * NPIX;
    const int b    = gpix >> 12;
    const int pinb = gpix & 4095;

    // ---------------- weights -> VGPR A-fragments (once) ----------------
    const int mt = wave;                       // backbone m-tile
    bf16x8 Abb_hi[2], Abb_lo[2];
    #pragma unroll
    for (int kt = 0; kt < 2; ++kt) {
        float v[8];
        #pragma unroll
        for (int j = 0; j < 8; ++j) {
            int k  = kt * 32 + lq * 8 + j;
            int ki = (k < CZ) ? k : (CZ - 1);
            float raw = Wb[(mt * 16 + ln) * CZ + ki];
            v[j] = (k < CZ) ? raw : 0.0f;
        }
        split8(v, Abb_hi[kt], Abb_lo[kt]);
    }
    // head weights, row-interleaved: tile row ln -> unit tile*4+(ln>>2), head ln&3
    const int hsel = ln & 3;
    const float* Whp = (hsel == 0) ? Wff1 : (hsel == 1) ? Wff2 : (hsel == 2) ? Wta : Wtb;
    bf16x8 Ah_hi[2][2], Ah_lo[2][2];
    #pragma unroll
    for (int i = 0; i < 2; ++i) {
        const int u = (wave * 2 + i) * 4 + (ln >> 2);
        #pragma unroll
        for (int kt = 0; kt < 2; ++kt) {
            float v[8];
            #pragma unroll
            for (int j = 0; j < 8; ++j) v[j] = Whp[u * BACKBONE + kt * 32 + lq * 8 + j];
            split8(v, Ah_hi[i][kt], Ah_lo[i][kt]);
        }
    }
    // biases in C/D layout
    float bbias[4];
    #pragma unroll
    for (int r = 0; r < 4; ++r) bbias[r] = bb[mt * 16 + lq * 4 + r];
    float hbias[2][4];
    #pragma unroll
    for (int i = 0; i < 2; ++i) {
        const int u2 = (wave * 2 + i) * 4 + lq;
        hbias[i][0] = bff1[u2]; hbias[i][1] = bff2[u2];
        hbias[i][2] = bta[u2];  hbias[i][3] = btb[u2];
    }

    // ---------------- prologue: zero z (h0 + K-pad), stage x_0 ----------
    for (int i = tid; i < NPIX * KPAD / 2; i += NTHREADS) {
        ((unsigned*)zhi)[i] = 0u;
        ((unsigned*)zlo)[i] = 0u;
    }
    __syncthreads();   // RACE FIX (R4 bug): zero-fill is cross-wave; must
                       // complete before any wave stages x_0 into z.
    const int xc = tid >> 4;           // channel 0..15
    const int xp = tid & 15;           // pixel 0..15
    const float* xb = x + (size_t)(b * CIN + xc) * (TSTEPS * HW) + pinb + xp;
    const int xoff = swoff(xp, xc);
    {
        float v = xb[0];
        unsigned short h = bf16_rne(v);
        zhi[xoff] = h;
        zlo[xoff] = bf16_rne(v - bf16_tof(h));
    }
    // per-lane hoisted offsets
    const int zrd0 = swoff(ln, lq * 8);            // kt=0 fragment read
    const int zrd1 = swoff(ln, 32 + lq * 8);       // kt=1
    const int awr  = swoff(ln, mt * 16 + lq * 4);  // phase1 act write (4 ushorts)
    float* outp = out + (size_t)(b * UNITS) * (TSTEPS * HW) + pinb + ln;
    __syncthreads();

    #pragma unroll 1
    for (int t = 0; t < TSTEPS; ++t) {
        // prefetch x_{t+1} (global; consumed in phase 2)
        const int tn = (t < TSTEPS - 1) ? t + 1 : TSTEPS - 1;
        const float xv = xb[tn * HW];

        // ---- phase 1: backbone 16x16 tile, 6 MFMA, lecun_tanh -> aT ----
        {
            bf16x8 B0h = __builtin_bit_cast(bf16x8, *(const short8*)&zhi[zrd0]);
            bf16x8 B0l = __builtin_bit_cast(bf16x8, *(const short8*)&zlo[zrd0]);
            bf16x8 B1h = __builtin_bit_cast(bf16x8, *(const short8*)&zhi[zrd1]);
            bf16x8 B1l = __builtin_bit_cast(bf16x8, *(const short8*)&zlo[zrd1]);
            float4v acc = {bbias[0], bbias[1], bbias[2], bbias[3]};
            acc = mfma16(Abb_hi[0], B0h, acc);
            acc = mfma16(Abb_hi[0], B0l, acc);
            acc = mfma16(Abb_lo[0], B0h, acc);
            acc = mfma16(Abb_hi[1], B1h, acc);
            acc = mfma16(Abb_hi[1], B1l, acc);
            acc = mfma16(Abb_lo[1], B1h, acc);
            short4v ph, pl;
            #pragma unroll
            for (int r = 0; r < 4; ++r) {
                float g = 1.7159f * tanh_fast(0.666f * acc[r]);
                unsigned short gh = bf16_rne(g);
                ph[r] = (short)gh;
                pl[r] = (short)bf16_rne(g - bf16_tof(gh));
            }
            *(short4v*)&ahi[awr] = ph;
            *(short4v*)&alo[awr] = pl;
        }
        __syncthreads();

        // ---- phase 2: stage x_{t+1}; 4-head interleaved GEMM + gate ----
        {
            // B fragments of backbone activations (shared by both m-tiles)
            bf16x8 B0h = __builtin_bit_cast(bf16x8, *(const short8*)&ahi[zrd0]);
            bf16x8 B0l = __builtin_bit_cast(bf16x8, *(const short8*)&alo[zrd0]);
            bf16x8 B1h = __builtin_bit_cast(bf16x8, *(const short8*)&ahi[zrd1]);
            bf16x8 B1l = __builtin_bit_cast(bf16x8, *(const short8*)&alo[zrd1]);

            // stage x_{t+1} into z x-rows (no z reader until next barrier)
            {
                unsigned short h = bf16_rne(xv);
                zhi[xoff] = h;
                zlo[xoff] = bf16_rne(xv - bf16_tof(h));
            }

            #pragma unroll
            for (int i = 0; i < 2; ++i) {
                float4v acc = {hbias[i][0], hbias[i][1], hbias[i][2], hbias[i][3]};
                acc = mfma16(Ah_hi[i][0], B0h, acc);
                acc = mfma16(Ah_hi[i][0], B0l, acc);
                acc = mfma16(Ah_lo[i][0], B0h, acc);
                acc = mfma16(Ah_hi[i][1], B1h, acc);
                acc = mfma16(Ah_hi[i][1], B1l, acc);
                acc = mfma16(Ah_lo[i][1], B1h, acc);
                // lane holds all 4 heads of unit u at pixel ln
                float f1 = tanh_fast(acc[0]);
                float f2 = tanh_fast(acc[1]);
                float ti = sigmoid_fast(acc[2] + acc[3]);
                float hn = f1 + ti * (f2 - f1);
                const int u = (wave * 2 + i) * 4 + lq;
                outp[(size_t)(u * TSTEPS + t) * HW] = hn;
                unsigned short hh = bf16_rne(hn);
                int ho = swoff(ln, CIN + u);
                zhi[ho] = hh;
                zlo[ho] = bf16_rne(hn - bf16_tof(hh));
            }
        }
        __syncthreads();
    }
}

extern "C" void kernel_launch(void* const* d_in, const int* in_sizes, int n_in,
                              void* d_out, int out_size, void* d_ws, size_t ws_size,
                              hipStream_t stream) {
    dim3 grid(4 * HW / NPIX);   // 1024 blocks -> 4 blocks/CU
    cfc_mfma_kernel<<<grid, NTHREADS, 0, stream>>>(
        (const float*)d_in[0], (const float*)d_in[1], (const float*)d_in[2],
        (const float*)d_in[3], (const float*)d_in[4], (const float*)d_in[5],
        (const float*)d_in[6], (const float*)d_in[7], (const float*)d_in[8],
        (const float*)d_in[9], (const float*)d_in[10],
        (float*)d_out);
}

// Round 6
// 171.394 us; speedup vs baseline: 4.5180x; 1.0219x over previous
//
#include <hip/hip_runtime.h>
#include <hip/hip_bf16.h>

// CfC / liquid-RNN scan on MFMA, R6. fp32 buffers (proven R2).
// R5 post-mortem: VALU-issue-bound (62% busy), dominated by hi/lo split
// packing + extra MFMA B-terms. R6: activations (x, a, h) stored HI-ONLY in
// LDS; weights keep hi+lo split (preloaded, free per-step). Each GEMM =
// (W_hi + W_lo) * B_hi = 2 MFMA/k-tile. Error: activation bf16 quantization
// ~2^-9/step into a contractive recurrence -> predicted absmax ~0.01 < 0.0199.
// Phase 2: all 4 heads as one GEMM, row-interleaved (row = u*4 + h); lane
// gets the 4 head values of one unit in its 4 acc regs -> in-register gate.
// 2 barriers/step. NPIX=16 -> 1024 blocks -> 4 blocks/CU (R5-proven).

#define CIN      16
#define UNITS    32
#define BACKBONE 64
#define CZ       48
#define TSTEPS   32
#define HW       4096
#define NPIX     16
#define NTHREADS 256
#define KPAD     64

typedef __attribute__((ext_vector_type(8))) short  short8;
typedef __attribute__((ext_vector_type(4))) short  short4v;
typedef __attribute__((ext_vector_type(8))) __bf16 bf16x8;
typedef __attribute__((ext_vector_type(4))) float  float4v;

__device__ __forceinline__ unsigned short bf16_rne(float f) {
    unsigned u = __float_as_uint(f);
    return (unsigned short)((u + 0x7FFFu + ((u >> 16) & 1u)) >> 16);
}
__device__ __forceinline__ float bf16_tof(unsigned short h) {
    return __uint_as_float(((unsigned)h) << 16);
}
__device__ __forceinline__ float tanh_fast(float x) {
    float e = __expf(2.0f * x);                 // saturates correctly
    return 1.0f - __fdividef(2.0f, e + 1.0f);
}
__device__ __forceinline__ float sigmoid_fast(float x) {
    return __fdividef(1.0f, 1.0f + __expf(-x));
}
__device__ __forceinline__ float4v mfma16(bf16x8 a, bf16x8 b, float4v c) {
    return __builtin_amdgcn_mfma_f32_16x16x32_bf16(a, b, c, 0, 0, 0);
}
__device__ __forceinline__ void split8(const float* v, bf16x8& hi, bf16x8& lo) {
    short8 sh, sl;
    #pragma unroll
    for (int j = 0; j < 8; ++j) {
        unsigned short h = bf16_rne(v[j]);
        sh[j] = (short)h;
        sl[j] = (short)bf16_rne(v[j] - bf16_tof(h));
    }
    hi = __builtin_bit_cast(bf16x8, sh);
    lo = __builtin_bit_cast(bf16x8, sl);
}
// element (pixel p, k) -> ushort offset; 16B chunks xor-swizzled by (p&7)
__device__ __forceinline__ int swoff(int p, int k) {
    return p * KPAD + ((((k >> 3) ^ (p & 7)) << 3) | (k & 7));
}

__global__ __launch_bounds__(NTHREADS, 4)
void cfc_mfma_kernel(const float* __restrict__ x,   const float* __restrict__ Wb,
                     const float* __restrict__ bb,
                     const float* __restrict__ Wff1, const float* __restrict__ bff1,
                     const float* __restrict__ Wff2, const float* __restrict__ bff2,
                     const float* __restrict__ Wta,  const float* __restrict__ bta,
                     const float* __restrict__ Wtb,  const float* __restrict__ btb,
                     float* __restrict__ out)
{
    __shared__ unsigned short zhi[NPIX * KPAD];   // z = [x_t; h], K-padded, bf16
    __shared__ unsigned short ahi[NPIX * KPAD];   // backbone activations, bf16

    const int tid  = threadIdx.x;
    const int wave = tid >> 6;
    const int lane = tid & 63;
    const int ln   = lane & 15;     // MFMA m/n
    const int lq   = lane >> 4;     // MFMA quad

    const int gpix = blockIdx.x * NPIX;
    const int b    = gpix >> 12;
    const int pinb = gpix & 4095;

    // ---------------- weights -> VGPR A-fragments (once), hi+lo ----------
    const int mt = wave;                       // backbone m-tile
    bf16x8 Abb_hi[2], Abb_lo[2];
    #pragma unroll
    for (int kt = 0; kt < 2; ++kt) {
        float v[8];
        #pragma unroll
        for (int j = 0; j < 8; ++j) {
            int k  = kt * 32 + lq * 8 + j;
            int ki = (k < CZ) ? k : (CZ - 1);
            float raw = Wb[(mt * 16 + ln) * CZ + ki];
            v[j] = (k < CZ) ? raw : 0.0f;
        }
        split8(v, Abb_hi[kt], Abb_lo[kt]);
    }
    // head weights, row-interleaved: tile row ln -> unit tile*4+(ln>>2), head ln&3
    const int hsel = ln & 3;
    const float* Whp = (hsel == 0) ? Wff1 : (hsel == 1) ? Wff2 : (hsel == 2) ? Wta : Wtb;
    bf16x8 Ah_hi[2][2], Ah_lo[2][2];
    #pragma unroll
    for (int i = 0; i < 2; ++i) {
        const int u = (wave * 2 + i) * 4 + (ln >> 2);
        #pragma unroll
        for (int kt = 0; kt < 2; ++kt) {
            float v[8];
            #pragma unroll
            for (int j = 0; j < 8; ++j) v[j] = Whp[u * BACKBONE + kt * 32 + lq * 8 + j];
            split8(v, Ah_hi[i][kt], Ah_lo[i][kt]);
        }
    }
    // biases in C/D layout
    float bbias[4];
    #pragma unroll
    for (int r = 0; r < 4; ++r) bbias[r] = bb[mt * 16 + lq * 4 + r];
    float hbias[2][4];
    #pragma unroll
    for (int i = 0; i < 2; ++i) {
        const int u2 = (wave * 2 + i) * 4 + lq;
        hbias[i][0] = bff1[u2]; hbias[i][1] = bff2[u2];
        hbias[i][2] = bta[u2];  hbias[i][3] = btb[u2];
    }

    // ---------------- prologue: zero z (h0 + K-pad), stage x_0 ----------
    for (int i = tid; i < NPIX * KPAD / 2; i += NTHREADS)
        ((unsigned*)zhi)[i] = 0u;
    __syncthreads();   // zero-fill is cross-wave; must finish before x_0 store
    const int xc = tid >> 4;           // channel 0..15
    const int xp = tid & 15;           // pixel 0..15
    const float* xb = x + (size_t)(b * CIN + xc) * (TSTEPS * HW) + pinb + xp;
    const int xoff = swoff(xp, xc);
    zhi[xoff] = bf16_rne(xb[0]);

    // hoisted per-lane offsets
    const int zrd0 = swoff(ln, lq * 8);            // kt=0 fragment read
    const int zrd1 = swoff(ln, 32 + lq * 8);       // kt=1
    const int awr  = swoff(ln, mt * 16 + lq * 4);  // phase1 act write (4 ushorts)
    const int u0   = (wave * 2 + 0) * 4 + lq;      // phase2 units
    const int u1   = (wave * 2 + 1) * 4 + lq;
    const int ho0  = swoff(ln, CIN + u0);          // h feedback stores
    const int ho1  = swoff(ln, CIN + u1);
    float* po0 = out + (size_t)((b * UNITS + u0) * TSTEPS) * HW + pinb + ln;
    float* po1 = out + (size_t)((b * UNITS + u1) * TSTEPS) * HW + pinb + ln;
    int xoffs = HW;                                // scalar offset of x_{t+1}
    __syncthreads();

    #pragma unroll 1
    for (int t = 0; t < TSTEPS; ++t) {
        // prefetch x_{t+1} (dummy re-read of x_31 on the last iter)
        const float xv = xb[xoffs];

        // ---- phase 1: backbone 16x16 tile, 4 MFMA, lecun_tanh -> aT ----
        {
            bf16x8 Z0 = __builtin_bit_cast(bf16x8, *(const short8*)&zhi[zrd0]);
            bf16x8 Z1 = __builtin_bit_cast(bf16x8, *(const short8*)&zhi[zrd1]);
            float4v acc = {bbias[0], bbias[1], bbias[2], bbias[3]};
            acc = mfma16(Abb_hi[0], Z0, acc);
            acc = mfma16(Abb_lo[0], Z0, acc);
            acc = mfma16(Abb_hi[1], Z1, acc);
            acc = mfma16(Abb_lo[1], Z1, acc);
            short4v ph;
            #pragma unroll
            for (int r = 0; r < 4; ++r)
                ph[r] = (short)bf16_rne(1.7159f * tanh_fast(0.666f * acc[r]));
            *(short4v*)&ahi[awr] = ph;
        }
        __syncthreads();

        // ---- phase 2: stage x_{t+1}; 4-head interleaved GEMM + gate ----
        {
            bf16x8 A0 = __builtin_bit_cast(bf16x8, *(const short8*)&ahi[zrd0]);
            bf16x8 A1 = __builtin_bit_cast(bf16x8, *(const short8*)&ahi[zrd1]);

            // stage x_{t+1} into z x-rows (no z reader until next barrier)
            zhi[xoff] = bf16_rne(xv);

            {   // tile 0 (units u0)
                float4v acc = {hbias[0][0], hbias[0][1], hbias[0][2], hbias[0][3]};
                acc = mfma16(Ah_hi[0][0], A0, acc);
                acc = mfma16(Ah_lo[0][0], A0, acc);
                acc = mfma16(Ah_hi[0][1], A1, acc);
                acc = mfma16(Ah_lo[0][1], A1, acc);
                float f1 = tanh_fast(acc[0]);
                float f2 = tanh_fast(acc[1]);
                float ti = sigmoid_fast(acc[2] + acc[3]);
                float hn = f1 + ti * (f2 - f1);
                *po0 = hn;  po0 += HW;
                zhi[ho0] = bf16_rne(hn);
            }
            {   // tile 1 (units u1)
                float4v acc = {hbias[1][0], hbias[1][1], hbias[1][2], hbias[1][3]};
                acc = mfma16(Ah_hi[1][0], A0, acc);
                acc = mfma16(Ah_lo[1][0], A0, acc);
                acc = mfma16(Ah_hi[1][1], A1, acc);
                acc = mfma16(Ah_lo[1][1], A1, acc);
                float f1 = tanh_fast(acc[0]);
                float f2 = tanh_fast(acc[1]);
                float ti = sigmoid_fast(acc[2] + acc[3]);
                float hn = f1 + ti * (f2 - f1);
                *po1 = hn;  po1 += HW;
                zhi[ho1] = bf16_rne(hn);
            }
        }
        __syncthreads();

        xoffs += (t < TSTEPS - 2) ? HW : 0;   // uniform scalar; clamp at x_31
    }
}

extern "C" void kernel_launch(void* const* d_in, const int* in_sizes, int n_in,
                              void* d_out, int out_size, void* d_ws, size_t ws_size,
                              hipStream_t stream) {
    dim3 grid(4 * HW / NPIX);   // 1024 blocks -> 4 blocks/CU
    cfc_mfma_kernel<<<grid, NTHREADS, 0, stream>>>(
        (const float*)d_in[0], (const float*)d_in[1], (const float*)d_in[2],
        (const float*)d_in[3], (const float*)d_in[4], (const float*)d_in[5],
        (const float*)d_in[6], (const float*)d_in[7], (const float*)d_in[8],
        (const float*)d_in[9], (const float*)d_in[10],
        (float*)d_out);
}